// Round 1
// baseline (342.555 us; speedup 1.0000x reference)
//
#include <hip/hip_runtime.h>
#include <hip/hip_bf16.h>
#include <stdint.h>

// irreps linear: 128x0e+128x1o+128x2e, per-block y[z,w,i] = a * sum_u W[u,w] x[z,u,i]
// Treated as GEMMs with M=(i,z), N=w(128), K=u(128). bf16 MFMA, f32 accum.

#define NROWS 100000
#define ROWLEN 1152

typedef __attribute__((ext_vector_type(8))) short bf16x8;
typedef __attribute__((ext_vector_type(4))) float f32x4;

__device__ __forceinline__ ushort f2b(float f) {
  union { float f; uint32_t u; } v; v.f = f;
  uint32_t r = v.u + 0x7FFFu + ((v.u >> 16) & 1u);  // RNE; inputs finite
  return (ushort)(r >> 16);
}

// One irrep block for one row-tile.
// D = ir dim, TM = rows per tile, MT = GEMM M-tile = TM*D (multiple of 16).
// xb/wb/ob are pre-offset to this block. LDS A layout: [m][u] bf16, row = 256 B,
// 16B-chunk XOR swizzle: chunk' = chunk ^ (m&7)  (G4 bank-conflict fix).
template<int D, int TM, int MT>
__device__ __forceinline__ void linpath(const float* __restrict__ xb,
                                        const float* __restrict__ wb,
                                        float* __restrict__ ob,
                                        int tile, char* lds)
{
  constexpr int CH = 128 * D;          // f32 per row in this block
  constexpr int MTILES = MT / 16;
  constexpr float ALPHA = 0.088388347648318447f;  // 128^-0.5

  const int tid  = threadIdx.x;
  const int lane = tid & 63;
  const int wv   = tid >> 6;           // 4 waves, each owns n-slice of 32
  const int z0   = tile * TM;
  const int l15  = lane & 15;
  const int kr   = ((lane >> 4) & 3) << 3;   // k sub-group base within 32

  // ---- weights -> registers (K=128 x N=32 slice per wave), ALPHA folded ----
  bf16x8 bfr[2][4];
  const int nbase = (wv << 5) + l15;
  #pragma unroll
  for (int nt = 0; nt < 2; ++nt)
    #pragma unroll
    for (int ks = 0; ks < 4; ++ks)
      #pragma unroll
      for (int j = 0; j < 8; ++j) {
        float f = wb[(ks * 32 + kr + j) * 128 + nbase + nt * 16] * ALPHA;
        bfr[nt][ks][j] = (short)f2b(f);
      }

  // ---- stage x tile -> LDS bf16 (m = i*TM + z_local) ----
  constexpr int TOT = TM * CH;                 // 18432 or 20480, divisible by 1024
  #pragma unroll
  for (int it = 0; it < TOT / 1024; ++it) {
    int e  = it * 1024 + (tid << 2);
    int zl = e / CH;
    int c  = e - zl * CH;
    int z  = z0 + zl;
    float4 v;
    if (z < NROWS) v = *(const float4*)(xb + (size_t)z * ROWLEN + c);
    else { v.x = 0.f; v.y = 0.f; v.z = 0.f; v.w = 0.f; }
    if (D == 1) {
      // 4 consecutive u, same m: pack -> 8B LDS write
      int m = zl, u = c;
      ushort4 p;
      p.x = f2b(v.x); p.y = f2b(v.y); p.z = f2b(v.z); p.w = f2b(v.w);
      int byte = m * 256 + ((((u >> 3) ^ (m & 7)) << 4) | ((u & 7) << 1));
      *(ushort4*)(lds + byte) = p;
    } else {
      float vv[4] = { v.x, v.y, v.z, v.w };
      #pragma unroll
      for (int j = 0; j < 4; ++j) {
        int cc = c + j;
        int u  = cc / D;
        int i  = cc - u * D;
        int m  = i * TM + zl;
        int byte = m * 256 + ((((u >> 3) ^ (m & 7)) << 4) | ((u & 7) << 1));
        *(ushort*)(lds + byte) = f2b(vv[j]);
      }
    }
  }
  __syncthreads();

  // ---- MFMA: D[m][n] += sum_u A[m][u] * B[u][n] ----
  f32x4 acc[MTILES][2];
  #pragma unroll
  for (int mt = 0; mt < MTILES; ++mt) {
    acc[mt][0] = f32x4{0.f, 0.f, 0.f, 0.f};
    acc[mt][1] = f32x4{0.f, 0.f, 0.f, 0.f};
  }
  #pragma unroll
  for (int ks = 0; ks < 4; ++ks) {
    const int u0 = (ks << 5) + kr;
    #pragma unroll
    for (int mt = 0; mt < MTILES; ++mt) {
      int m = (mt << 4) + l15;
      int byte = m * 256 + (((u0 >> 3) ^ (m & 7)) << 4);
      bf16x8 a = *(const bf16x8*)(lds + byte);
      acc[mt][0] = __builtin_amdgcn_mfma_f32_16x16x32_bf16(a, bfr[0][ks], acc[mt][0], 0, 0, 0);
      acc[mt][1] = __builtin_amdgcn_mfma_f32_16x16x32_bf16(a, bfr[1][ks], acc[mt][1], 0, 0, 0);
    }
  }

  // ---- store: C/D layout col=lane&15 (n), row=(lane>>4)*4+r (m) ----
  const int rbase = (lane >> 4) << 2;
  #pragma unroll
  for (int mt = 0; mt < MTILES; ++mt) {
    const int i  = (mt * 16) / TM;     // constant per tile (TM % 16 == 0)
    const int zb = (mt * 16) % TM;
    #pragma unroll
    for (int nt = 0; nt < 2; ++nt) {
      int col = (nbase + nt * 16) * D + i;
      #pragma unroll
      for (int r = 0; r < 4; ++r) {
        int z = z0 + zb + rbase + r;
        if (z < NROWS) ob[(size_t)z * ROWLEN + col] = acc[mt][nt][r];
      }
    }
  }
}

constexpr int NWG1 = (NROWS + 143) / 144;  // 695
constexpr int NWG3 = (NROWS + 47)  / 48;   // 2084
constexpr int NWG5 = (NROWS + 31)  / 32;   // 3125

__global__ __launch_bounds__(256)
void linear_irreps_kernel(const float* __restrict__ x, const float* __restrict__ w,
                          float* __restrict__ out)
{
  extern __shared__ __align__(16) char lds[];
  int wg = blockIdx.x;
  if (wg < NWG1) {
    linpath<1, 144, 144>(x,        w,          out,        wg,               lds);
  } else if (wg < NWG1 + NWG3) {
    linpath<3, 48, 144>(x + 128,   w + 16384,  out + 128,  wg - NWG1,        lds);
  } else {
    linpath<5, 32, 160>(x + 512,   w + 32768,  out + 512,  wg - NWG1 - NWG3, lds);
  }
}

extern "C" void kernel_launch(void* const* d_in, const int* in_sizes, int n_in,
                              void* d_out, int out_size, void* d_ws, size_t ws_size,
                              hipStream_t stream) {
  const float* x = (const float*)d_in[0];
  const float* w = (const float*)d_in[1];
  float* out = (float*)d_out;
  (void)in_sizes; (void)n_in; (void)out_size; (void)d_ws; (void)ws_size;
  dim3 grid(NWG1 + NWG3 + NWG5);
  dim3 block(256);
  hipLaunchKernelGGL(linear_irreps_kernel, grid, block, 40960, stream, x, w, out);
}

// Round 2
// 206.096 us; speedup vs baseline: 1.6621x; 1.6621x over previous
//
#include <hip/hip_runtime.h>
#include <stdint.h>

// irreps linear: 128x0e+128x1o+128x2e, per-block y[z,w,i] = a * sum_u W[u,w] x[z,u,i]
// GEMMs with M=(i,z), N=w(128), K=u(128). bf16 MFMA, f32 accum.
// Persistent WGs (768 = 3/CU), W in registers once, double-buffered LDS with
// register prefetch of the next tile (T14), 8B deinterleave LDS writes.

#define NROWS 100000
#define ROWLEN 1152

typedef __attribute__((ext_vector_type(8))) short bf16x8;
typedef __attribute__((ext_vector_type(4))) float f32x4;
typedef __attribute__((ext_vector_type(4))) ushort u16x4;

__device__ __forceinline__ ushort f2b(float f) {
  union { float f; uint32_t u; } v; v.f = f;
  uint32_t r = v.u + 0x7FFFu + ((v.u >> 16) & 1u);  // RNE; inputs finite
  return (ushort)(r >> 16);
}

// ---- staging helpers ----------------------------------------------------
// Chunk = 4 consecutive u x D i's = 4D consecutive floats of x's natural row.
// 32 chunks per row; thread handles TM/8 chunks per tile.

template<int D, int TM, bool G>
__device__ __forceinline__ void load_tile(const float* __restrict__ xb, int t,
                                          int tid, f32x4 (&vf)[TM / 8][D])
{
  #pragma unroll
  for (int p = 0; p < TM / 8; ++p) {
    int ch = p * 256 + tid;
    int zl = ch >> 5, cc = ch & 31;
    int z  = t * TM + zl;
    const float* src = xb + (size_t)z * ROWLEN + cc * 4 * D;
    #pragma unroll
    for (int j = 0; j < D; ++j) {
      f32x4 v = {0.f, 0.f, 0.f, 0.f};
      if (!G || z < NROWS) v = *(const f32x4*)(src + 4 * j);
      vf[p][j] = v;
    }
  }
}

// LDS A layout: [m][u] bf16, row = 256 B, 16B-chunk XOR swizzle chunk^=(m&7).
template<int D, int TM>
__device__ __forceinline__ void write_tile(char* __restrict__ buf, int tid,
                                           f32x4 (&vf)[TM / 8][D])
{
  #pragma unroll
  for (int p = 0; p < TM / 8; ++p) {
    int ch = p * 256 + tid;
    int zl = ch >> 5, cc = ch & 31;
    #pragma unroll
    for (int i = 0; i < D; ++i) {
      int m = i * TM + zl;
      u16x4 pk;
      #pragma unroll
      for (int u = 0; u < 4; ++u) {
        int e = i + D * u;            // compile-time after unroll
        pk[u] = f2b(vf[p][e >> 2][e & 3]);
      }
      int byte = m * 256 + ((((cc >> 1) ^ (m & 7)) << 4) | ((cc & 1) << 3));
      *(u16x4*)(buf + byte) = pk;
    }
  }
}

template<bool G, int D, int TM, int MTILES>
__device__ __forceinline__ void store_tile(float* __restrict__ ob, int z0,
                                           int lane, int nbase,
                                           f32x4 (&acc)[MTILES][2])
{
  const int rbase = ((lane >> 4) & 3) << 2;
  #pragma unroll
  for (int mt = 0; mt < MTILES; ++mt) {
    #pragma unroll
    for (int r = 0; r < 4; ++r) {
      int m  = mt * 16 + rbase + r;
      int i  = m / TM, zl = m % TM;
      int z  = z0 + zl;
      if (G && z >= NROWS) continue;
      float* orow = ob + (size_t)z * ROWLEN + i;
      orow[(size_t)nbase * D]        = acc[mt][0][r];
      orow[(size_t)(nbase + 16) * D] = acc[mt][1][r];
    }
  }
}

// ---- persistent per-irrep path ------------------------------------------
template<int D, int TM, bool GUARD, int NWGS>
__device__ __forceinline__ void linpath(const float* __restrict__ xb,
                                        const float* __restrict__ wb,
                                        float* __restrict__ ob,
                                        int wgid, char* lds)
{
  constexpr int MT     = TM * D;
  constexpr int MTILES = MT / 16;
  constexpr int PT     = TM / 8;
  constexpr int NTILES = (NROWS + TM - 1) / TM;
  constexpr int BUFB   = MT * 256;
  constexpr float ALPHA = 0.088388347648318447f;  // 128^-0.5

  const int tid   = threadIdx.x;
  const int lane  = tid & 63;
  const int wv    = tid >> 6;
  const int l15   = lane & 15;
  const int kr    = ((lane >> 4) & 3) << 3;
  const int nbase = (wv << 5) + l15;

  // ---- weights -> registers once per WG (K=128 x N=32 per wave), ALPHA folded
  bf16x8 bfr[2][4];
  #pragma unroll
  for (int nt = 0; nt < 2; ++nt)
    #pragma unroll
    for (int ks = 0; ks < 4; ++ks)
      #pragma unroll
      for (int j = 0; j < 8; ++j)
        bfr[nt][ks][j] =
            (short)f2b(wb[(ks * 32 + kr + j) * 128 + nbase + nt * 16] * ALPHA);

  char* buf0 = lds;
  char* buf1 = lds + BUFB;

  // ---- prologue: stage first tile ----
  int t0 = wgid;
  {
    f32x4 vf[PT][D];
    if (GUARD && t0 == NTILES - 1) load_tile<D, TM, true>(xb, t0, tid, vf);
    else                           load_tile<D, TM, false>(xb, t0, tid, vf);
    write_tile<D, TM>(buf0, tid, vf);
  }
  __syncthreads();

  int cur = 0;
  for (int t = t0; t < NTILES; t += NWGS) {
    char* bc = cur ? buf1 : buf0;
    char* bn = cur ? buf0 : buf1;
    const int tn = t + NWGS;
    const bool have = tn < NTILES;

    // 1. issue next tile's global loads into regs (latency hides under MFMA)
    f32x4 vf[PT][D];
    if (have) {
      if (GUARD && tn == NTILES - 1) load_tile<D, TM, true>(xb, tn, tid, vf);
      else                           load_tile<D, TM, false>(xb, tn, tid, vf);
    }

    // 2. MFMA on current buffer
    f32x4 acc[MTILES][2];
    #pragma unroll
    for (int mt = 0; mt < MTILES; ++mt) {
      acc[mt][0] = f32x4{0.f, 0.f, 0.f, 0.f};
      acc[mt][1] = f32x4{0.f, 0.f, 0.f, 0.f};
    }
    #pragma unroll
    for (int ks = 0; ks < 4; ++ks) {
      const int chunkbase = ks * 4 + ((lane >> 4) & 3);  // (ks*32+kr)>>3
      #pragma unroll
      for (int mt = 0; mt < MTILES; ++mt) {
        int m = (mt << 4) + l15;
        int byte = m * 256 + ((chunkbase ^ (m & 7)) << 4);
        bf16x8 a = *(const bf16x8*)(bc + byte);
        acc[mt][0] = __builtin_amdgcn_mfma_f32_16x16x32_bf16(a, bfr[0][ks], acc[mt][0], 0, 0, 0);
        acc[mt][1] = __builtin_amdgcn_mfma_f32_16x16x32_bf16(a, bfr[1][ks], acc[mt][1], 0, 0, 0);
      }
    }

    // 3. convert + LDS-write next tile (global loads have landed by now)
    if (have) write_tile<D, TM>(bn, tid, vf);

    // 4. store current tile's output
    if (GUARD && t == NTILES - 1)
      store_tile<true, D, TM, MTILES>(ob, t * TM, lane, nbase, acc);
    else
      store_tile<false, D, TM, MTILES>(ob, t * TM, lane, nbase, acc);

    __syncthreads();
    cur ^= 1;
  }
}

// WG split ~ proportional to bytes (1:3:5), tuned so per-WG work is even.
constexpr int NW1 = 84;    // D=1, TM=64, 1563 tiles
constexpr int NW3 = 254;   // D=3, TM=16, 6250 tiles
constexpr int NW5 = 430;   // D=5, TM=16, 6250 tiles

__global__ __launch_bounds__(256, 3)
void linear_irreps_kernel(const float* __restrict__ x, const float* __restrict__ w,
                          float* __restrict__ out)
{
  extern __shared__ __align__(16) char lds[];
  int wg = blockIdx.x;
  if (wg < NW1) {
    linpath<1, 64, true,  NW1>(x,       w,         out,       wg,             lds);
  } else if (wg < NW1 + NW3) {
    linpath<3, 16, false, NW3>(x + 128, w + 16384, out + 128, wg - NW1,       lds);
  } else {
    linpath<5, 16, false, NW5>(x + 512, w + 32768, out + 512, wg - NW1 - NW3, lds);
  }
}

extern "C" void kernel_launch(void* const* d_in, const int* in_sizes, int n_in,
                              void* d_out, int out_size, void* d_ws, size_t ws_size,
                              hipStream_t stream) {
  const float* x = (const float*)d_in[0];
  const float* w = (const float*)d_in[1];
  float* out = (float*)d_out;
  (void)in_sizes; (void)n_in; (void)out_size; (void)d_ws; (void)ws_size;
  dim3 grid(NW1 + NW3 + NW5);
  dim3 block(256);
  hipLaunchKernelGGL(linear_irreps_kernel, grid, block, 40960, stream, x, w, out);
}